// Round 15
// baseline (67.454 us; speedup 1.0000x reference)
//
#include <hip/hip_runtime.h>
#include <hip/hip_bf16.h>

typedef __attribute__((ext_vector_type(8))) short short8;
typedef __attribute__((ext_vector_type(4))) float f32x4;
typedef __attribute__((ext_vector_type(2))) float f32x2;

#define BKS      6      // log2 nodes per bucket
#define BKN      64     // nodes per bucket
#define EPB      4096   // edges per bin block
#define NBMAX    1024   // max buckets (N <= 65536)
#define CAPB_MAX 3072   // max edges per bucket (mean ~1023, huge margin)

__device__ __forceinline__ unsigned short f2bf(float f) {
    unsigned u = __builtin_bit_cast(unsigned, f);
    u += 0x7fffu + ((u >> 16) & 1u);
    return (unsigned short)(u >> 16);
}
__device__ __forceinline__ float bf2f(unsigned short b) {
    return __builtin_bit_cast(float, ((unsigned)b) << 16);
}

// ---------------------------------------------------------------------------
// K0: prepbin — dedicated roles (round-15):
//   blocks [0,EB): bin with FULL in-LDS bucket sort -> coalesced gbuf bursts.
//   blocks [EB,..): x -> bf16 xb + fp8 xq; W -> Wp fragment-pack.
// pack = src|(dst&63)<<24.
// ---------------------------------------------------------------------------
__global__ __launch_bounds__(256) void prepbin_kernel(
    const float* __restrict__ x, unsigned short* __restrict__ xb,
    unsigned char* __restrict__ xq,
    const float* __restrict__ W, unsigned short* __restrict__ Wp,
    const int* __restrict__ src, const int* __restrict__ dst,
    unsigned* gcur, unsigned* __restrict__ gbuf,
    int E, int nb, int capb, int nx8)
{
    int tid = threadIdx.x;
    int EB  = (E + EPB - 1) / EPB;

    if ((int)blockIdx.x >= EB) {
        // ---- convert role ----
        int gid = (blockIdx.x - EB) * 256 + tid;
        if (gid < nx8) {
            const float4* p = (const float4*)(x + (size_t)gid * 8);
            float4 lo = p[0], hi = p[1];
            short8 v;
            v[0] = (short)f2bf(lo.x); v[1] = (short)f2bf(lo.y);
            v[2] = (short)f2bf(lo.z); v[3] = (short)f2bf(lo.w);
            v[4] = (short)f2bf(hi.x); v[5] = (short)f2bf(hi.y);
            v[6] = (short)f2bf(hi.z); v[7] = (short)f2bf(hi.w);
            *(short8*)(xb + (size_t)gid * 8) = v;

            int p0 = 0, p1 = 0;
            p0 = __builtin_amdgcn_cvt_pk_fp8_f32(lo.x, lo.y, p0, false);
            p0 = __builtin_amdgcn_cvt_pk_fp8_f32(lo.z, lo.w, p0, true);
            p1 = __builtin_amdgcn_cvt_pk_fp8_f32(hi.x, hi.y, p1, false);
            p1 = __builtin_amdgcn_cvt_pk_fp8_f32(hi.z, hi.w, p1, true);
            uint2 q; q.x = (unsigned)p0; q.y = (unsigned)p1;
            *(uint2*)(xq + (size_t)gid * 8) = q;
        }
        if (gid < 4096) {   // W -> Wp fragment order (1 KB wave B-loads)
            const float4* p = (const float4*)(W + (size_t)gid * 8);
            float4 lo = p[0], hi = p[1];
            short8 v;
            v[0] = (short)f2bf(lo.x); v[1] = (short)f2bf(lo.y);
            v[2] = (short)f2bf(lo.z); v[3] = (short)f2bf(lo.w);
            v[4] = (short)f2bf(hi.x); v[5] = (short)f2bf(hi.y);
            v[6] = (short)f2bf(hi.z); v[7] = (short)f2bf(hi.w);
            int r    = gid >> 5;
            int c0   = (gid & 31) << 3;
            int ct   = r >> 4;
            int arow = r & 15;
            int ks   = c0 >> 5;
            int kgrp = (c0 >> 3) & 3;
            int l    = arow | (kgrp << 4);
            *(short8*)(Wp + (((size_t)(ct * 8 + ks) * 64 + l) * 8)) = v;
        }
        return;
    }

    // ---- bin role: LDS bucket-sort of this block's EPB edges ----
    __shared__ unsigned hist[NBMAX];     // per-bucket count (rank source)
    __shared__ unsigned excl[NBMAX];     // exclusive scan of hist
    __shared__ unsigned sbase[NBMAX];    // global base per bucket
    __shared__ unsigned part[256];
    __shared__ unsigned sedge[EPB];      // bucket-sorted packed edges
    __shared__ unsigned short sbkt[EPB]; // bucket id per sorted slot

    for (int t = tid; t < nb; t += 256) hist[t] = 0u;
    __syncthreads();

    int e0 = blockIdx.x * EPB + tid;
    unsigned pk[EPB / 256];
    unsigned short bk[EPB / 256], pp[EPB / 256];
#pragma unroll
    for (int it = 0; it < EPB / 256; ++it) {
        int e = e0 + it * 256;
        bk[it] = 0xFFFFu;
        if (e < E) {
            int d = dst[e];
            unsigned b = (unsigned)d >> BKS;
            pk[it] = (unsigned)src[e] | ((unsigned)(d & (BKN - 1)) << 24);
            pp[it] = (unsigned short)atomicAdd(&hist[b], 1u);  // rank in bucket
            bk[it] = (unsigned short)b;
        }
    }
    __syncthreads();

    // exclusive scan of hist[0..nb) -> excl
    int ch = (nb + 255) >> 8;
    int b0 = tid * ch;
    int b1 = b0 + ch; if (b1 > nb) b1 = nb;
    unsigned s = 0;
    for (int i = b0; i < b1; ++i) s += hist[i];
    part[tid] = s;
    __syncthreads();
#pragma unroll
    for (int off = 1; off < 256; off <<= 1) {
        unsigned t = (tid >= off) ? part[tid - off] : 0u;
        __syncthreads();
        part[tid] += t;
        __syncthreads();
    }
    unsigned run = part[tid] - s;
    for (int i = b0; i < b1; ++i) { excl[i] = run; run += hist[i]; }
    __syncthreads();

    // LDS scatter into sorted order
#pragma unroll
    for (int it = 0; it < EPB / 256; ++it) {
        if (bk[it] != 0xFFFFu) {
            unsigned b = bk[it];
            unsigned pos = excl[b] + pp[it];
            sedge[pos] = pk[it];
            sbkt[pos]  = (unsigned short)b;
        }
    }
    // reserve global space: one atomic per (block,bucket)
    for (int t = tid; t < nb; t += 256)
        sbase[t] = hist[t] ? atomicAdd(&gcur[t], hist[t]) : 0u;
    __syncthreads();

    // coalesced write-out in sorted order
    unsigned total = excl[nb - 1] + hist[nb - 1];
    for (unsigned i = tid; i < total; i += 256) {
        unsigned b   = sbkt[i];
        unsigned off = sbase[b] + (i - excl[b]);
        if (off < (unsigned)capb) gbuf[(size_t)b * capb + off] = sedge[i];
    }
}

// ---------------------------------------------------------------------------
// K1: agg+gemm fused — one block (512 thr, 8 waves) per 64-node bucket.
// Stage A: in-LDS CSR. Stage B: quarter-owns-node fp8 gather (128 B/row),
// 4-deep clamped, HW cvt decode, f32 accumulate, bf16 LDS mean.
// Stage C: GEMM+ReLU (fragment-packed Wp, bf16 A).  [round-14, known-good]
// ---------------------------------------------------------------------------
__global__ __launch_bounds__(512) void agg_gemm_kernel(
    const unsigned short* __restrict__ xb,
    const unsigned char* __restrict__ xq,
    const unsigned* __restrict__ gbuf,
    const unsigned* __restrict__ gcur,
    const unsigned short* __restrict__ Wp,
    float* __restrict__ out, int N, int capb)
{
    __shared__ unsigned cnt[BKN];
    __shared__ unsigned degs[BKN];
    __shared__ unsigned cur[BKN];
    __shared__ unsigned elist[CAPB_MAX];
    __shared__ unsigned short aggs[BKN][136];

    int tid = threadIdx.x;
    int b   = blockIdx.x;
    unsigned cntB = gcur[b];
    if (cntB > (unsigned)capb) cntB = (unsigned)capb;
    const unsigned* bb = gbuf + (size_t)b * capb;

    // ---- stage A: in-LDS CSR ----
    if (tid < BKN) cnt[tid] = 0u;
    __syncthreads();
    for (unsigned i = tid; i < cntB; i += 512)
        atomicAdd(&cnt[bb[i] >> 24], 1u);
    __syncthreads();
    if (tid < BKN) degs[tid] = cnt[tid];
    __syncthreads();
#pragma unroll
    for (int off = 1; off < BKN; off <<= 1) {
        unsigned t = (tid < BKN && tid >= off) ? cnt[tid - off] : 0u;
        __syncthreads();
        if (tid < BKN) cnt[tid] += t;
        __syncthreads();
    }
    if (tid < BKN) cur[tid] = cnt[tid] - degs[tid];
    __syncthreads();
    for (unsigned i = tid; i < cntB; i += 512) {
        unsigned pk = bb[i];
        unsigned p  = atomicAdd(&cur[pk >> 24], 1u);
        elist[p] = pk & 0x00FFFFFFu;
    }
    __syncthreads();

    // ---- stage B: quarter-owns-node fp8 gather -> LDS bf16 mean ----
    int wv = tid >> 6, l = tid & 63;
    int q4 = l >> 4, ql = l & 15;
    int base = b << BKS;

#pragma unroll
    for (int pass = 0; pass < BKN / 32; ++pass) {
        int r0 = pass * 32 + wv * 4 + q4;
        unsigned endi  = cnt[r0];
        unsigned dg    = degs[r0];
        unsigned start = endi - dg;
        float acc[8] = {0.f, 0.f, 0.f, 0.f, 0.f, 0.f, 0.f, 0.f};

        for (unsigned eb = start; eb < endi; eb += 4) {
            unsigned last = endi - 1;
            unsigned e1 = eb + 1, e2 = eb + 2, e3 = eb + 3;
            float w0 = 1.0f;
            float w1 = (e1 < endi) ? 1.0f : 0.0f;
            float w2 = (e2 < endi) ? 1.0f : 0.0f;
            float w3 = (e3 < endi) ? 1.0f : 0.0f;
            unsigned i1 = (e1 < endi) ? e1 : last;
            unsigned i2 = (e2 < endi) ? e2 : last;
            unsigned i3 = (e3 < endi) ? e3 : last;
            unsigned s0 = elist[eb], s1 = elist[i1];
            unsigned s2 = elist[i2], s3 = elist[i3];
            uint2 u0 = *(const uint2*)(xq + (size_t)s0 * 128 + ql * 8);
            uint2 u1 = *(const uint2*)(xq + (size_t)s1 * 128 + ql * 8);
            uint2 u2 = *(const uint2*)(xq + (size_t)s2 * 128 + ql * 8);
            uint2 u3 = *(const uint2*)(xq + (size_t)s3 * 128 + ql * 8);
#define ACC8(u, w)                                                            \
            {                                                                 \
                f32x2 a0 = __builtin_amdgcn_cvt_pk_f32_fp8((int)(u).x, false);\
                f32x2 a1 = __builtin_amdgcn_cvt_pk_f32_fp8((int)(u).x, true); \
                f32x2 a2 = __builtin_amdgcn_cvt_pk_f32_fp8((int)(u).y, false);\
                f32x2 a3 = __builtin_amdgcn_cvt_pk_f32_fp8((int)(u).y, true); \
                acc[0] = fmaf(w, a0.x, acc[0]); acc[1] = fmaf(w, a0.y, acc[1]);\
                acc[2] = fmaf(w, a1.x, acc[2]); acc[3] = fmaf(w, a1.y, acc[3]);\
                acc[4] = fmaf(w, a2.x, acc[4]); acc[5] = fmaf(w, a2.y, acc[5]);\
                acc[6] = fmaf(w, a3.x, acc[6]); acc[7] = fmaf(w, a3.y, acc[7]);\
            }
            ACC8(u0, w0); ACC8(u1, w1); ACC8(u2, w2); ACC8(u3, w3);
#undef ACC8
        }

        float inv = dg ? 1.0f / (float)dg : 1.0f;
        short8 st;
#pragma unroll
        for (int j = 0; j < 8; ++j) st[j] = (short)f2bf(acc[j] * inv);
        *(short8*)&aggs[r0][ql * 8] = st;
    }
    __syncthreads();

    // ---- stage C: GEMM + ReLU for this bucket's 64 rows ----
    int w    = tid >> 6;
    int rt   = w >> 1;
    int cth  = w & 1;
    int arow = l & 15;
    int kgrp = l >> 4;
    int row  = base + rt * 16 + arow;
    bool rok = row < N;

    short8 afrag[8];
#pragma unroll
    for (int ks = 0; ks < 4; ++ks) {
        short8 a = {};
        if (rok) a = *(const short8*)(xb + (size_t)row * 128 + ks * 32 + kgrp * 8);
        afrag[ks] = a;
    }
#pragma unroll
    for (int ks = 0; ks < 4; ++ks)
        afrag[4 + ks] = *(const short8*)&aggs[rt * 16 + arow][ks * 32 + kgrp * 8];

    f32x4 acc[4];
#pragma unroll
    for (int c = 0; c < 4; ++c) acc[c] = (f32x4){0.f, 0.f, 0.f, 0.f};

#pragma unroll
    for (int ks = 0; ks < 8; ++ks) {
        short8 a = afrag[ks];
#pragma unroll
        for (int c = 0; c < 4; ++c) {
            int ct = cth * 4 + c;
            const short8* bp =
                (const short8*)(Wp + (((size_t)(ct * 8 + ks) * 64 + l) * 8));
            acc[c] = __builtin_amdgcn_mfma_f32_16x16x32_bf16(a, *bp, acc[c], 0, 0, 0);
        }
    }

#pragma unroll
    for (int c = 0; c < 4; ++c) {
#pragma unroll
        for (int r = 0; r < 4; ++r) {
            int orow = base + rt * 16 + kgrp * 4 + r;
            if (orow < N) {
                out[(size_t)orow * 128 + (cth * 4 + c) * 16 + arow] =
                    fmaxf(acc[c][r], 0.0f);
            }
        }
    }
}

// ---------------------------------------------------------------------------
extern "C" void kernel_launch(void* const* d_in, const int* in_sizes, int n_in,
                              void* d_out, int out_size, void* d_ws, size_t ws_size,
                              hipStream_t stream) {
    const float* x  = (const float*)d_in[0];
    const int* src  = (const int*)d_in[1];
    const int* dst  = (const int*)d_in[2];
    const float* W  = (const float*)d_in[4];

    int N = in_sizes[0] / 128;
    int E = in_sizes[1];
    float* out = (float*)d_out;

    int nb = (N + BKN - 1) >> BKS;
    int capb = 2 * (E / (nb > 0 ? nb : 1)) + 1024;
    capb = (capb + 63) & ~63;
    if (capb > CAPB_MAX) capb = CAPB_MAX;

    char* ws = (char*)d_ws;
    size_t o = 0;
    auto carve = [&](size_t bytes) {
        char* p = ws + o;
        o += (bytes + 255) & ~(size_t)255;
        return p;
    };
    unsigned* gcur     = (unsigned*)carve((size_t)nb * 4);
    unsigned* gbuf     = (unsigned*)carve((size_t)nb * capb * 4);
    unsigned short* Wp = (unsigned short*)carve(128 * 256 * 2);
    unsigned short* xb = (unsigned short*)carve((size_t)N * 128 * 2);
    unsigned char* xq  = (unsigned char*)carve((size_t)N * 128);
    (void)ws_size;   // ~30 MB used; harness provides 256 MiB

    int nx8 = N * 16;
    int EB  = (E + EPB - 1) / EPB;          // 196 bin blocks
    int CB  = (nx8 + 255) / 256;            // 3125 convert blocks
    if (CB < 16) CB = 16;                   // cover W pack

    hipMemsetAsync(gcur, 0, (size_t)nb * 4, stream);
    prepbin_kernel<<<EB + CB, 256, 0, stream>>>(x, xb, xq, W, Wp, src, dst,
                                                gcur, gbuf, E, nb, capb, nx8);
    agg_gemm_kernel<<<nb, 512, 0, stream>>>(xb, xq, gbuf, gcur, Wp, out, N, capb);
}